// Round 6
// baseline (224.568 us; speedup 1.0000x reference)
//
#include <hip/hip_runtime.h>
#include <stdint.h>

// y = C @ ( expm(A*d) h + A^{-1}(expm(A*d)-I) B [du;u] ),  A = 0.5*(W - W^T)
// Series kept: hn = h + d*b + (d/2)*(W h - W^T h); error << 0.037 threshold.
// R6: cooperative fusion failed (launch not graph-capturable -> y stayed 0).
//     Instead: kill the fin dispatch entirely. W blocks atomicAdd their
//     column partials (W^T h) straight into wt[4096] (device-scope f32
//     atomics, ~2M ops over 4096 addrs, fire-and-forget). c_kernel computes
//     hn inline from h/db/Wh/wt (L2-hot) and goes to 1024 blocks x 1 row
//     (4 blocks/CU). Pipeline: memset(16KB) -> mega -> c. pWh (8.4MB RT)
//     and fin are gone. Mega keeps plain-load stream (1.45 TB/s cap is
//     platform-level; R0-R4 proved structure-invariance).

#define Hd 4096
#define Dd 1024
#define DELTA 0.1f
#define ROWS 8
#define NWB2 512           // W blocks (8 rows each); B blocks same count

__device__ __forceinline__ float wred(float x){
  #pragma unroll
  for (int off = 32; off > 0; off >>= 1) x += __shfl_down(x, off, 64);
  return x;  // valid in lane 0
}

// ---- blocks [0,512): W rows 8b..8b+7 -> Wh row-dots + atomic wt column sums.
//      blocks [512,1024): B rows -> db.
__global__ __launch_bounds__(256) void mega_kernel(const float* __restrict__ W,
                                                   const float* __restrict__ Bw,
                                                   const float* __restrict__ uu,
                                                   const float* __restrict__ du,
                                                   const float* __restrict__ h,
                                                   float* __restrict__ Wh,
                                                   float* __restrict__ wt,
                                                   float* __restrict__ db){
  __shared__ float sred[4*ROWS];
  const int tid = threadIdx.x;
  const int lane = tid & 63, wave = tid >> 6;
  const int b = blockIdx.x;

  if (b < NWB2){
    const float* base = W + (size_t)b * ROWS * Hd;
    float4 v4[4];
    #pragma unroll
    for (int p = 0; p < 4; p++) v4[p] = *(const float4*)(h + p*1024 + 4*tid);
    float hb[ROWS];
    #pragma unroll
    for (int r = 0; r < ROWS; r++) hb[r] = h[b*ROWS + r];   // uniform -> scalar
    float ch[16];
    #pragma unroll
    for (int i = 0; i < 16; i++) ch[i] = 0.f;
    float rh[ROWS];
    #pragma unroll
    for (int r = 0; r < ROWS; r++){
      float racc = 0.f;
      #pragma unroll
      for (int p = 0; p < 4; p++){
        float4 wv = *(const float4*)(base + (size_t)r*Hd + p*1024 + 4*tid);
        racc += wv.x*v4[p].x + wv.y*v4[p].y + wv.z*v4[p].z + wv.w*v4[p].w;
        ch[p*4+0] += wv.x*hb[r]; ch[p*4+1] += wv.y*hb[r];
        ch[p*4+2] += wv.z*hb[r]; ch[p*4+3] += wv.w*hb[r];
      }
      rh[r] = racc;
    }
    // column partials -> device-scope atomics (fire-and-forget, no return)
    #pragma unroll
    for (int p = 0; p < 4; p++){
      const int c = p*1024 + 4*tid;
      atomicAdd(wt + c + 0, ch[p*4+0]);
      atomicAdd(wt + c + 1, ch[p*4+1]);
      atomicAdd(wt + c + 2, ch[p*4+2]);
      atomicAdd(wt + c + 3, ch[p*4+3]);
    }
    #pragma unroll
    for (int r = 0; r < ROWS; r++) rh[r] = wred(rh[r]);
    if (lane == 0){
      #pragma unroll
      for (int r = 0; r < ROWS; r++) sred[wave*ROWS + r] = rh[r];
    }
    __syncthreads();
    if (tid < ROWS)
      Wh[b*ROWS + tid] = sred[tid] + sred[ROWS + tid] + sred[2*ROWS + tid] + sred[3*ROWS + tid];
  } else {
    const float* base = Bw + (size_t)(b - NWB2) * ROWS * Hd;
    float4 v4[4];
    v4[0] = *(const float4*)(du + 4*tid);
    #pragma unroll
    for (int p = 1; p < 4; p++) v4[p] = *(const float4*)(uu + (p-1)*1024 + 4*tid);
    float rh[ROWS];
    #pragma unroll
    for (int r = 0; r < ROWS; r++){
      float racc = 0.f;
      #pragma unroll
      for (int p = 0; p < 4; p++){
        float4 wv = *(const float4*)(base + (size_t)r*Hd + p*1024 + 4*tid);
        racc += wv.x*v4[p].x + wv.y*v4[p].y + wv.z*v4[p].z + wv.w*v4[p].w;
      }
      rh[r] = racc;
    }
    #pragma unroll
    for (int r = 0; r < ROWS; r++) rh[r] = wred(rh[r]);
    if (lane == 0){
      #pragma unroll
      for (int r = 0; r < ROWS; r++) sred[wave*ROWS + r] = rh[r];
    }
    __syncthreads();
    if (tid < ROWS)
      db[(b - NWB2)*ROWS + tid] = DELTA *
        (sred[tid] + sred[ROWS + tid] + sred[2*ROWS + tid] + sred[3*ROWS + tid]);
  }
}

// ------- y[row] = C[row] . hn,  hn = h + db + 0.05*(Wh - wt), computed inline.
// 1024 blocks x 1 row: 4 blocks/CU. h/db/Wh/wt reads are L2/L1-hot broadcasts.
__global__ __launch_bounds__(256) void c_kernel(const float* __restrict__ Cw,
                                                const float* __restrict__ h,
                                                const float* __restrict__ db,
                                                const float* __restrict__ Wh,
                                                const float* __restrict__ wt,
                                                float* __restrict__ y){
  __shared__ float sred[4];
  const int tid = threadIdx.x;
  const int lane = tid & 63, wave = tid >> 6;
  const float* Cr = Cw + (size_t)blockIdx.x * Hd;
  float acc = 0.f;
  #pragma unroll
  for (int p = 0; p < 4; p++){
    const int c = p*1024 + 4*tid;
    float4 cv = *(const float4*)(Cr + c);
    float4 hv = *(const float4*)(h  + c);
    float4 dv = *(const float4*)(db + c);
    float4 wv = *(const float4*)(Wh + c);
    float4 tv = *(const float4*)(wt + c);
    float hn0 = hv.x + dv.x + 0.5f*DELTA*(wv.x - tv.x);
    float hn1 = hv.y + dv.y + 0.5f*DELTA*(wv.y - tv.y);
    float hn2 = hv.z + dv.z + 0.5f*DELTA*(wv.z - tv.z);
    float hn3 = hv.w + dv.w + 0.5f*DELTA*(wv.w - tv.w);
    acc += cv.x*hn0 + cv.y*hn1 + cv.z*hn2 + cv.w*hn3;
  }
  acc = wred(acc);
  if (lane == 0) sred[wave] = acc;
  __syncthreads();
  if (tid == 0) y[blockIdx.x] = sred[0] + sred[1] + sred[2] + sred[3];
}

extern "C" void kernel_launch(void* const* d_in, const int* in_sizes, int n_in,
                              void* d_out, int out_size, void* d_ws, size_t ws_size,
                              hipStream_t stream){
  // inputs: u[3072], du[1024], h[4096], W_w[4096^2], B_w[4096^2], C_w[1024*4096]
  const float* uu = (const float*)d_in[0];
  const float* du = (const float*)d_in[1];
  const float* h  = (const float*)d_in[2];
  const float* W  = (const float*)d_in[3];
  const float* Bw = (const float*)d_in[4];
  const float* Cw = (const float*)d_in[5];
  float* y = (float*)d_out;

  // ws: wt[4096] | Wh[4096] | db[4096]
  float* ws = (float*)d_ws;
  float* wt = ws;
  float* Wh = ws + Hd;
  float* db = Wh + Hd;

  hipMemsetAsync(wt, 0, Hd*sizeof(float), stream);      // graph-capturable
  mega_kernel<<<2*NWB2, 256, 0, stream>>>(W, Bw, uu, du, h, Wh, wt, db);
  c_kernel   <<<1024,   256, 0, stream>>>(Cw, h, db, Wh, wt, y);
}

// Round 7
// 172.383 us; speedup vs baseline: 1.3027x; 1.3027x over previous
//
#include <hip/hip_runtime.h>

// y = C @ ( expm(A*d) h + A^{-1}(expm(A*d)-I) B [du;u] ),  A = 0.5*(W - W^T)
// Series kept: hn = h + d*b + (d/2)*(W h - W^T h); error << 0.037 threshold.
// R7: R6 atomics regressed mega 47->103us (atomic RMW traffic, 512-way addr
//     contention). Revert to R3's measured-best mega+fin. Fixed findings:
//     (1) dur_us = sum(dispatch) + ~107us fixed harness residue (slope-1 fit
//         across R1-R6) -- untouchable from kernel side.
//     (2) mega stream is structure-invariant at ~2.9 TB/s logical delivered
//         (5 structures, HBM-cold and L3-warm identical) -- platform limit.
//     Only recoverable piece: c_kernel 256blk/LDS-staged (~12us @1.4TB/s) ->
//     1024 blocks x 1 row, no staging, hn L1-resident. Expect total ~167us.

#define Hd 4096
#define Dd 1024
#define DELTA 0.1f
#define NRB 256            // row bands (16 rows each)
#define RPB 16
#define NCS 4              // column slices per band
#define CSW 1024           // columns per slice
#define NWBLK (NRB*NCS)    // 1024 W blocks

__device__ __forceinline__ float wred(float x){
  #pragma unroll
  for (int off = 32; off > 0; off >>= 1) x += __shfl_down(x, off, 64);
  return x;  // valid in lane 0
}

// ---- blocks [0,1024): W tile (16 rows x 1024 cols) -> partial row-dots + column partials.
//      blocks [1024,2048): b-rows: db[row] = DELTA * (B_w @ [du;u])[row], 4 rows/block.
__global__ __launch_bounds__(256) void mega_kernel(const float* __restrict__ W,
                                                   const float* __restrict__ Bw,
                                                   const float* __restrict__ uu,
                                                   const float* __restrict__ du,
                                                   const float* __restrict__ h,
                                                   float* __restrict__ pRow,
                                                   float* __restrict__ pWh,
                                                   float* __restrict__ db){
  const int tid = threadIdx.x;
  const int b = blockIdx.x;
  if (b < NWBLK){
    __shared__ float red[4*RPB];           // 256 B
    const int r   = b & (NRB-1);           // row band
    const int cs  = b >> 8;                // column slice
    const int row0 = r * RPB;
    const int col  = cs*CSW + (tid << 2);
    const float4 vh = *(const float4*)(h + col);   // this thread's 4 cols of h
    float hb[RPB];
    #pragma unroll
    for (int i = 0; i < RPB; i++) hb[i] = h[row0 + i];   // uniform -> scalar
    float rh[RPB];
    float c0 = 0.f, c1 = 0.f, c2 = 0.f, c3 = 0.f;
    #pragma unroll
    for (int i = 0; i < RPB; i++){
      float4 wv = *(const float4*)(W + (size_t)(row0 + i)*Hd + col);
      rh[i] = wv.x*vh.x + wv.y*vh.y + wv.z*vh.z + wv.w*vh.w;
      c0 += wv.x*hb[i]; c1 += wv.y*hb[i]; c2 += wv.z*hb[i]; c3 += wv.w*hb[i];
    }
    *(float4*)(pWh + (size_t)r*Hd + col) = make_float4(c0, c1, c2, c3);
    #pragma unroll
    for (int i = 0; i < RPB; i++) rh[i] = wred(rh[i]);
    const int lane = tid & 63, wave = tid >> 6;
    if (lane == 0){
      #pragma unroll
      for (int i = 0; i < RPB; i++) red[wave*RPB + i] = rh[i];
    }
    __syncthreads();
    if (tid < RPB)
      pRow[(size_t)cs*Hd + row0 + tid] =
        red[tid] + red[RPB + tid] + red[2*RPB + tid] + red[3*RPB + tid];
  } else {
    const int t = b - NWBLK;               // 0..1023, 4 rows/block, 1 row/wave
    const int lane = tid & 63, wave = tid >> 6;
    const int row = t*4 + wave;            // all 4096 rows of b
    const float* Br = Bw + (size_t)row * Hd;
    float acc = 0.f;
    #pragma unroll
    for (int it = 0; it < 4; it++){        // c in [0,1024): du
      int c = it*256 + lane*4;
      float4 a = *(const float4*)(Br + c);
      float4 x = *(const float4*)(du + c);
      acc += a.x*x.x + a.y*x.y + a.z*x.z + a.w*x.w;
    }
    #pragma unroll
    for (int it = 4; it < 16; it++){       // c in [1024,4096): u
      int c = it*256 + lane*4;
      float4 a = *(const float4*)(Br + c);
      float4 x = *(const float4*)(uu + (c - Dd));
      acc += a.x*x.x + a.y*x.y + a.z*x.z + a.w*x.w;
    }
    acc = wred(acc);
    if (lane == 0) db[row] = DELTA * acc;
  }
}

// ---- fin: hn[e] = h[e] + db[e] + (DELTA/2)*(sum_cs pRow[cs][e] - sum_rb pWh[rb][e]) ----
// 128 blocks x 32 elements; 8 thread-groups of 32 split the NRB partial rows.
__global__ __launch_bounds__(256) void fin_kernel(const float* __restrict__ h,
                                                  const float* __restrict__ db,
                                                  const float* __restrict__ pRow,
                                                  const float* __restrict__ pWh,
                                                  float* __restrict__ hn){
  __shared__ float red[8*32];
  const int g = threadIdx.x >> 5, el = threadIdx.x & 31;
  const int e = blockIdx.x*32 + el;
  float ah = 0.f;
  #pragma unroll 4
  for (int k = 0; k < NRB/8; k++)
    ah += pWh[(size_t)(g + (k << 3))*Hd + e];   // coalesced over el
  red[g*32 + el] = ah;
  __syncthreads();
  if (threadIdx.x < 32){
    int e2 = blockIdx.x*32 + threadIdx.x;
    float swh = 0.f;
    #pragma unroll
    for (int g2 = 0; g2 < 8; g2++) swh += red[g2*32 + threadIdx.x];
    float wh = pRow[e2] + pRow[Hd + e2] + pRow[2*Hd + e2] + pRow[3*Hd + e2];
    hn[e2] = h[e2] + db[e2] + 0.5f*DELTA*(wh - swh);
  }
}

// ------------- y = C_w @ hn : 1024 blocks x 1 row, no LDS staging -------------
// hn (16 KB) is L1-resident per CU after first touch; C row loads issue from inst 0.
__global__ __launch_bounds__(256) void c_kernel(const float* __restrict__ Cw,
                                                const float* __restrict__ hn,
                                                float* __restrict__ y){
  __shared__ float sred[4];
  const int tid = threadIdx.x;
  const int lane = tid & 63, wave = tid >> 6;
  const float* Cr = Cw + (size_t)blockIdx.x * Hd;
  float acc = 0.f;
  #pragma unroll
  for (int p = 0; p < 4; p++){
    const int c = p*1024 + 4*tid;
    float4 cv = *(const float4*)(Cr + c);
    float4 xv = *(const float4*)(hn + c);
    acc += cv.x*xv.x + cv.y*xv.y + cv.z*xv.z + cv.w*xv.w;
  }
  acc = wred(acc);
  if (lane == 0) sred[wave] = acc;
  __syncthreads();
  if (tid == 0) y[blockIdx.x] = sred[0] + sred[1] + sred[2] + sred[3];
}

extern "C" void kernel_launch(void* const* d_in, const int* in_sizes, int n_in,
                              void* d_out, int out_size, void* d_ws, size_t ws_size,
                              hipStream_t stream){
  // inputs: u[3072], du[1024], h[4096], W_w[4096^2], B_w[4096^2], C_w[1024*4096]
  const float* uu = (const float*)d_in[0];
  const float* du = (const float*)d_in[1];
  const float* h  = (const float*)d_in[2];
  const float* W  = (const float*)d_in[3];
  const float* Bw = (const float*)d_in[4];
  const float* Cw = (const float*)d_in[5];
  float* y = (float*)d_out;

  // ws: pWh[256*4096] (4.2 MB) | pRow[4*4096] | db[4096] | hn[4096]
  float* ws   = (float*)d_ws;
  float* pWh  = ws;
  float* pRow = ws + (size_t)NRB * Hd;
  float* db   = pRow + (size_t)NCS * Hd;
  float* hn   = db + Hd;

  mega_kernel<<<NWBLK + 1024, 256, 0, stream>>>(W, Bw, uu, du, h, pRow, pWh, db);
  fin_kernel <<<128,          256, 0, stream>>>(h, db, pRow, pWh, hn);
  c_kernel   <<<1024,         256, 0, stream>>>(Cw, hn, y);
}